// Round 9
// baseline (222.222 us; speedup 1.0000x reference)
//
#include <hip/hip_runtime.h>
#include <hip/hip_bf16.h>

#define N_ROWS 131072
#define DIM 64
#define K_CODES 1024
#define NTILES 64
#define TPP 4                     // tiles per phase
#define NPHASE (NTILES / TPP)     // 16
#define MARGIN 4e-5f
#define LIST_CAP 65536

typedef short short8 __attribute__((ext_vector_type(8)));
typedef float f32x4 __attribute__((ext_vector_type(4)));
typedef const __attribute__((address_space(1))) void* gptr_t;
typedef __attribute__((address_space(3))) void* lptr_t;

__device__ __forceinline__ unsigned short f2bf(float f) {
    unsigned u = __float_as_uint(f);
    return (unsigned short)((u + 0x7fffu + ((u >> 16) & 1u)) >> 16);  // RNE
}
__device__ __forceinline__ float bf2f(unsigned short h) {
    return __uint_as_float(((unsigned)h) << 16);
}

// ws: byte 0: cnt u32, byte 4: loss f32, float idx 4..1027: esq,
//     byte 8192: B panel 256KB (64 tiles x 4 chunks x 64 lanes x 8 bf16),
//     byte 270336: fixup list u32[65536]

// prep: thread t = (k, c): k = code, c = chunk in {eh0, eh1, el0, el1}.
__global__ void vq_prep(const float* __restrict__ emb, float* __restrict__ esq,
                        unsigned short* __restrict__ wsB,
                        unsigned int* __restrict__ cnt, float* __restrict__ loss) {
#pragma clang fp contract(off)
    const int t = blockIdx.x * blockDim.x + threadIdx.x;
    if (t == 0) { *cnt = 0u; *loss = 0.f; }
    const int k = t >> 2, c = t & 3;
    if (k >= K_CODES) return;
    const float* e = emb + (size_t)k * DIM;

    if (c == 0) {   // np-exact esq (elementwise square, pairwise 8-acc chain)
        float ee[DIM];
        #pragma unroll
        for (int d = 0; d < DIM; ++d) { float v = e[d]; ee[d] = v * v; }
        float r[8];
        #pragma unroll
        for (int j = 0; j < 8; ++j) r[j] = ee[j];
        #pragma unroll
        for (int i = 8; i < DIM; i += 8)
            #pragma unroll
            for (int j = 0; j < 8; ++j) r[j] = r[j] + ee[i + j];
        esq[k] = ((r[0]+r[1]) + (r[2]+r[3])) + ((r[4]+r[5]) + (r[6]+r[7]));
    }

    const int off = (c & 1) * 32, sel = c >> 1;
    unsigned short val[32];
    #pragma unroll
    for (int j = 0; j < 32; ++j) {
        float v = e[off + j];
        unsigned short h = f2bf(v);
        val[j] = sel ? f2bf(v - bf2f(h)) : h;
    }
    const int tile = k >> 4, n = k & 15;
    #pragma unroll
    for (int g = 0; g < 4; ++g) {
        short8 s;
        #pragma unroll
        for (int j = 0; j < 8; ++j) s[j] = (short)val[g*8 + j];
        *reinterpret_cast<short8*>(wsB + ((size_t)((tile*4 + c)*64 + g*16 + n)) * 8) = s;
    }
}

__global__ __launch_bounds__(256, 3) void vq_mfma(const float* __restrict__ x,
        const float* __restrict__ emb, const float* __restrict__ esq,
        const unsigned short* __restrict__ wsB, float* __restrict__ out,
        unsigned int* __restrict__ cnt, unsigned int* __restrict__ list,
        float* __restrict__ loss) {
    const int tid = threadIdx.x;
    const int lane = tid & 63;
    const int w = tid >> 6;
    const int g = lane >> 4, res = lane & 15;
    const int rowbase = blockIdx.x * 128 + w * 32;   // 32 rows per wave (2 rgs)

    // double-buffered staged B: 2 x 4 tiles x 4KB; + argmin combine arrays
    __shared__ __align__(16) unsigned char sB[2][TPP * 4096];
    __shared__ int s_idx[128];
    __shared__ int s_flag[128];

    // stage phase p into buffer buf: 16KB, 4 x 16B per thread, linear copy
    // (LDS dst = wave-uniform base + lane*16 ✓)
    const unsigned char* wsBb = (const unsigned char*)wsB;
    auto stage = [&](int p, int buf) {
        #pragma unroll
        for (int i = 0; i < 4; ++i) {
            const int off = i * 4096 + w * 1024 + lane * 16;
            __builtin_amdgcn_global_load_lds((gptr_t)(wsBb + p * (TPP*4096) + off),
                                             (lptr_t)&sB[buf][off], 16, 0, 0);
        }
    };

    stage(0, 0);   // latency hides under A-frag build

    // A-frags: lane holds row (rowbase + rg*16 + res), k-slots g*8+j
    short8 Ah[2][2], Al[2][2];
    #pragma unroll
    for (int rg = 0; rg < 2; ++rg) {
        const float* xr = x + (size_t)(rowbase + rg*16 + res) * DIM;
        #pragma unroll
        for (int h = 0; h < 2; ++h) {
            float4 v0 = *reinterpret_cast<const float4*>(xr + h*32 + g*8);
            float4 v1 = *reinterpret_cast<const float4*>(xr + h*32 + g*8 + 4);
            float xv[8] = {v0.x, v0.y, v0.z, v0.w, v1.x, v1.y, v1.z, v1.w};
            short8 sh, sl;
            #pragma unroll
            for (int j = 0; j < 8; ++j) {
                unsigned short hb = f2bf(xv[j]);
                sh[j] = (short)hb;
                sl[j] = (short)f2bf(xv[j] - bf2f(hb));
            }
            Ah[rg][h] = sh; Al[rg][h] = sl;
        }
    }

    float b1[8], b2[8]; int bi[8];
    #pragma unroll
    for (int s = 0; s < 8; ++s) { b1[s] = 1e30f; b2[s] = 1e30f; bi[s] = 0; }

    __syncthreads();   // phase-0 staged (compiler drains vmcnt before barrier)

    int buf = 0;
    for (int p = 0; p < NPHASE; ++p) {
        if (p + 1 < NPHASE) stage(p + 1, buf ^ 1);
        #pragma unroll
        for (int tt = 0; tt < TPP; ++tt) {
            const int ct = p * TPP + tt;
            short8 B[4];
            #pragma unroll
            for (int c = 0; c < 4; ++c)
                B[c] = *reinterpret_cast<const short8*>(
                           &sB[buf][tt*4096 + c*1024 + lane*16]);
            const float esqv = esq[ct*16 + res];
            const int kcur = ct*16 + res;
            #pragma unroll
            for (int rg = 0; rg < 2; ++rg) {
                f32x4 acc = {0.f, 0.f, 0.f, 0.f};
                acc = __builtin_amdgcn_mfma_f32_16x16x32_bf16(Ah[rg][0], B[0], acc, 0,0,0); // hh
                acc = __builtin_amdgcn_mfma_f32_16x16x32_bf16(Ah[rg][1], B[1], acc, 0,0,0);
                acc = __builtin_amdgcn_mfma_f32_16x16x32_bf16(Ah[rg][0], B[2], acc, 0,0,0); // hl
                acc = __builtin_amdgcn_mfma_f32_16x16x32_bf16(Ah[rg][1], B[3], acc, 0,0,0);
                acc = __builtin_amdgcn_mfma_f32_16x16x32_bf16(Al[rg][0], B[0], acc, 0,0,0); // lh
                acc = __builtin_amdgcn_mfma_f32_16x16x32_bf16(Al[rg][1], B[1], acc, 0,0,0);
                #pragma unroll
                for (int r = 0; r < 4; ++r) {
                    float v = fmaf(-2.0f, acc[r], esqv);  // d~ = esq - 2*dot
                    const int s = rg*4 + r;
                    bool lt = v < b1[s];
                    b2[s] = fminf(fmaxf(v, b1[s]), b2[s]);
                    b1[s] = fminf(v, b1[s]);
                    bi[s] = lt ? kcur : bi[s];
                }
            }
        }
        __syncthreads();   // stage(p+1) landed; all waves done reading buf
        buf ^= 1;
    }

    // top-2 merge across the 16 code-residue lanes
    #pragma unroll
    for (int m = 1; m < 16; m <<= 1) {
        #pragma unroll
        for (int s = 0; s < 8; ++s) {
            float ob1 = __shfl_xor(b1[s], m, 64);
            float ob2 = __shfl_xor(b2[s], m, 64);
            int   obi = __shfl_xor(bi[s], m, 64);
            float nb2 = fminf(fmaxf(b1[s], ob1), fminf(b2[s], ob2));
            bi[s] = (ob1 < b1[s]) ? obi : bi[s];
            b1[s] = fminf(b1[s], ob1);
            b2[s] = nb2;
        }
    }

    if (res == 0) {
        #pragma unroll
        for (int s = 0; s < 8; ++s) {   // row_local = w*32 + rg*16 + g*4 + r
            const int rl = w*32 + (s >> 2)*16 + g*4 + (s & 3);
            s_idx[rl] = bi[s];
            s_flag[rl] = (b2[s] - b1[s] < MARGIN) ? 1 : 0;
        }
    }
    __syncthreads();

    // epilogue: 2 threads per row (32 dims each)
    const int rl = tid >> 1, half = tid & 1;
    const int row = blockIdx.x * 128 + rl;
    const int idx = s_idx[rl];
    float lsum = 0.f;
    if (s_flag[rl]) {
        if (half == 0) {
            unsigned slot = atomicAdd(cnt, 1u);
            if (slot < LIST_CAP) list[slot] = (unsigned)row;
        }
    } else {
        const float* xr = x + (size_t)row * DIM + half*32;
        const float* qr = emb + (size_t)idx * DIM + half*32;
        float* orow = out + (size_t)row * DIM + half*32;
        #pragma unroll
        for (int i = 0; i < 8; ++i) {
            float4 xv = reinterpret_cast<const float4*>(xr)[i];
            float4 qv = reinterpret_cast<const float4*>(qr)[i];
            float df0 = qv.x - xv.x, df1 = qv.y - xv.y;
            float df2 = qv.z - xv.z, df3 = qv.w - xv.w;
            lsum = fmaf(df0, df0, lsum); lsum = fmaf(df1, df1, lsum);
            lsum = fmaf(df2, df2, lsum); lsum = fmaf(df3, df3, lsum);
            float4 o = {xv.x + df0, xv.y + df1, xv.z + df2, xv.w + df3};
            reinterpret_cast<float4*>(orow)[i] = o;
        }
        if (half == 0) out[(size_t)N_ROWS * DIM + row] = (float)idx;
    }
    #pragma unroll
    for (int off = 32; off > 0; off >>= 1) lsum += __shfl_down(lsum, off, 64);
    if (lane == 0) atomicAdd(loss, lsum);
}

// exact np-chain re-scan for flagged rows: one wave per row, first-min over all K
__global__ void vq_fixup(const float* __restrict__ x, const float* __restrict__ emb,
                         const float* __restrict__ esq,
                         const unsigned int* __restrict__ cnt,
                         const unsigned int* __restrict__ list,
                         float* __restrict__ out, float* __restrict__ loss) {
#pragma clang fp contract(off)
    const int lane = threadIdx.x & 63;
    const int wid = (blockIdx.x * blockDim.x + threadIdx.x) >> 6;
    const int nw = (256 * 256) >> 6;
    unsigned count = *cnt;
    if (count > LIST_CAP) count = LIST_CAP;
    for (unsigned i = wid; i < count; i += nw) {
        const int row = (int)list[i];
        float xv[DIM];
        const float4* xp = reinterpret_cast<const float4*>(x + (size_t)row * DIM);
        #pragma unroll
        for (int q = 0; q < 16; ++q) {
            float4 v = xp[q];
            xv[4*q+0] = v.x; xv[4*q+1] = v.y; xv[4*q+2] = v.z; xv[4*q+3] = v.w;
        }
        float xsq;
        {   // np-exact xsq
            float xx[DIM];
            #pragma unroll
            for (int d = 0; d < DIM; ++d) xx[d] = xv[d] * xv[d];
            float r[8];
            #pragma unroll
            for (int j = 0; j < 8; ++j) r[j] = xx[j];
            #pragma unroll
            for (int ii = 8; ii < DIM; ii += 8)
                #pragma unroll
                for (int j = 0; j < 8; ++j) r[j] = r[j] + xx[ii + j];
            xsq = ((r[0]+r[1]) + (r[2]+r[3])) + ((r[4]+r[5]) + (r[6]+r[7]));
        }
        float best = INFINITY; int bidx = 0x7fffffff;
        for (int t = 0; t < K_CODES / 64; ++t) {
            const int k = lane + t * 64;   // ascending per lane
            const float* ek = emb + (size_t)k * DIM;
            float a0 = 0.f, a1 = 0.f, a2 = 0.f, a3 = 0.f;
            #pragma unroll
            for (int c = 0; c < DIM; c += 16)
                #pragma unroll
                for (int b = 12; b >= 0; b -= 4) {   // np block order
                    const int d = c + b;
                    a0 = a0 + xv[d+0] * ek[d+0];
                    a1 = a1 + xv[d+1] * ek[d+1];
                    a2 = a2 + xv[d+2] * ek[d+2];
                    a3 = a3 + xv[d+3] * ek[d+3];
                }
            float dot = (a0 + a1) + (a2 + a3);
            float tt = xsq + esq[k];
            float dist = tt - 2.0f * dot;
            if (dist < best) { best = dist; bidx = k; }
        }
        #pragma unroll
        for (int m = 1; m < 64; m <<= 1) {   // lexicographic (dist, idx) min
            float ob = __shfl_xor(best, m, 64);
            int   oi = __shfl_xor(bidx, m, 64);
            if (ob < best || (ob == best && oi < bidx)) { best = ob; bidx = oi; }
        }
        const float xd = x[(size_t)row * DIM + lane];
        const float qd = emb[(size_t)bidx * DIM + lane];
        const float df = qd - xd;
        out[(size_t)row * DIM + lane] = xd + df;
        if (lane == 0) out[(size_t)N_ROWS * DIM + row] = (float)bidx;
        float l2 = df * df;
        #pragma unroll
        for (int off = 32; off > 0; off >>= 1) l2 += __shfl_down(l2, off, 64);
        if (lane == 0) atomicAdd(loss, l2);
    }
}

__global__ void vq_final(const float* __restrict__ loss_acc, float* __restrict__ out_loss) {
    if (threadIdx.x == 0 && blockIdx.x == 0)
        out_loss[0] = loss_acc[0] / (float)((size_t)N_ROWS * DIM);
}

extern "C" void kernel_launch(void* const* d_in, const int* in_sizes, int n_in,
                              void* d_out, int out_size, void* d_ws, size_t ws_size,
                              hipStream_t stream) {
    const float* x   = (const float*)d_in[0];
    const float* emb = (const float*)d_in[1];
    float* out = (float*)d_out;

    unsigned int* cnt  = (unsigned int*)d_ws;
    float* loss        = (float*)d_ws + 1;
    float* esq         = (float*)d_ws + 4;
    unsigned short* wsB = (unsigned short*)((char*)d_ws + 8192);
    unsigned int* list = (unsigned int*)((char*)d_ws + 270336);

    vq_prep<<<dim3(16), dim3(256), 0, stream>>>(emb, esq, wsB, cnt, loss);
    vq_mfma<<<dim3(N_ROWS / 128), dim3(256), 0, stream>>>(x, emb, esq, wsB, out,
                                                          cnt, list, loss);
    vq_fixup<<<dim3(256), dim3(256), 0, stream>>>(x, emb, esq, cnt, list, out, loss);
    vq_final<<<dim3(1), dim3(1), 0, stream>>>(loss, out + (size_t)N_ROWS * DIM + N_ROWS);
}